// Round 2
// baseline (318.083 us; speedup 1.0000x reference)
//
#include <hip/hip_runtime.h>

// CognitiveLorenzField: 500-step scan over DIM=65536 vectors.
// Exact 2D-subspace reduction: vL_t = p_t*vL0, vJ_t = q_t*vL0 + r_t*vJ0.
// Only two dot products (L00, L01) are needed; the per-step update is scalar.
// The timed cost is streaming 262 MB of output writes (memory-bound).

#define DIM 65536
#define STEPS 500
#define DIM4 (DIM / 4)          // 16384 float4 per vector
#define CHUNKS 16               // expand: chunks per step, 1024 float4 each

typedef float vfloat4 __attribute__((ext_vector_type(4)));  // native vec for nontemporal builtins

__device__ constexpr float ALPHA0 = 1.0f;
__device__ constexpr float BETA_GAME = 0.2f;
__device__ constexpr float GAMMA_C = 0.5f;
__device__ constexpr float SIGMA = 10.0f;
__device__ constexpr float RHO = 28.0f;
__device__ constexpr float LORENZ_BETA = 8.0f / 3.0f;
__device__ constexpr float DT = 0.01f;
__device__ constexpr float EPS = 1e-8f;

// ws layout (floats):
//   [0..63]      per-block partial of vL0.vL0
//   [64..127]    per-block partial of vL0.vJ0
//   [128..627]   p[t]
//   [628..1127]  q[t]
//   [1128..1627] r[t]

__global__ __launch_bounds__(256) void dot_partials(const vfloat4* __restrict__ vL,
                                                    const vfloat4* __restrict__ vJ,
                                                    float* __restrict__ ws) {
    int tid = threadIdx.x;
    int idx = blockIdx.x * 256 + tid;          // 64 blocks * 256 = 16384 = DIM4
    vfloat4 a = vL[idx];
    vfloat4 b = vJ[idx];
    float sL  = a.x * a.x + a.y * a.y + a.z * a.z + a.w * a.w;
    float sLJ = a.x * b.x + a.y * b.y + a.z * b.z + a.w * b.w;
    #pragma unroll
    for (int off = 32; off > 0; off >>= 1) {
        sL  += __shfl_down(sL,  off, 64);
        sLJ += __shfl_down(sLJ, off, 64);
    }
    __shared__ float redL[4], redLJ[4];
    int wave = tid >> 6;
    if ((tid & 63) == 0) { redL[wave] = sL; redLJ[wave] = sLJ; }
    __syncthreads();
    if (tid == 0) {
        ws[blockIdx.x]      = redL[0] + redL[1] + redL[2] + redL[3];
        ws[64 + blockIdx.x] = redLJ[0] + redLJ[1] + redLJ[2] + redLJ[3];
    }
}

__global__ __launch_bounds__(64) void recurrence(float* __restrict__ ws,
                                                 float* __restrict__ outZ) {
    int tid = threadIdx.x;                      // one wave of 64
    float sL  = ws[tid];
    float sLJ = ws[64 + tid];
    #pragma unroll
    for (int off = 32; off > 0; off >>= 1) {
        sL  += __shfl_down(sL,  off, 64);
        sLJ += __shfl_down(sLJ, off, 64);
    }
    if (tid != 0) return;
    const float L00 = sL;
    const float L01 = sLJ;
    float* pA = ws + 128;
    float* qA = ws + 628;
    float* rA = ws + 1128;
    float x = 1.f, y = 1.f, z = 1.f;
    float p = 1.f, q = 0.f, r = 1.f;
    for (int t = 0; t < STEPS; ++t) {
        // Lorenz Euler step (independent short chain)
        float dx = SIGMA * (y - x);
        float dy = x * (RHO - z) - y;
        float dz = x * y - LORENZ_BETA * z;
        x += DT * dx;
        y += DT * dy;
        z += DT * dz;
        float alpha = ALPHA0 + GAMMA_C * z;
        // projection coefficient in the 2D subspace
        float dot = p * (q * L00 + r * L01);
        float nsq = p * p * L00 + EPS;
        float c   = dot * __builtin_amdgcn_rcpf(nsq);   // ~1ulp rcp, threshold is huge
        // vL_new = p_new * vL0
        float pn = p * (1.0f + DT * (alpha * (c - 1.0f) + BETA_GAME));
        // vJ_new = q_new * vL0 + r_new * vJ0
        float decay = 1.0f - DT * (alpha + BETA_GAME);
        float qn = q * decay + DT * p * (alpha * c + BETA_GAME);
        float rn = r * decay;
        p = pn; q = qn; r = rn;
        pA[t] = p; qA[t] = q; rA[t] = r;
        outZ[t] = z;
    }
}

__global__ __launch_bounds__(256) void expand(const vfloat4* __restrict__ vL,
                                              const vfloat4* __restrict__ vJ,
                                              const float* __restrict__ ws,
                                              vfloat4* __restrict__ outL,
                                              vfloat4* __restrict__ outJ) {
    int t     = blockIdx.x >> 4;      // / CHUNKS
    int chunk = blockIdx.x & 15;      // % CHUNKS
    float p = ws[128 + t];
    float q = ws[628 + t];
    float r = ws[1128 + t];
    int  base = chunk * 1024;         // float4 index within the vector
    long tb   = (long)t * DIM4;
    #pragma unroll
    for (int k = 0; k < 4; ++k) {
        int idx = base + k * 256 + threadIdx.x;       // lane-contiguous, coalesced
        vfloat4 a = vL[idx];
        vfloat4 b = vJ[idx];
        vfloat4 oL = p * a;
        vfloat4 oJ = q * a + r * b;
        __builtin_nontemporal_store(oL, &outL[tb + idx]);
        __builtin_nontemporal_store(oJ, &outJ[tb + idx]);
    }
}

extern "C" void kernel_launch(void* const* d_in, const int* in_sizes, int n_in,
                              void* d_out, int out_size, void* d_ws, size_t ws_size,
                              hipStream_t stream) {
    const vfloat4* vL = (const vfloat4*)d_in[0];
    const vfloat4* vJ = (const vfloat4*)d_in[1];
    float* out = (float*)d_out;
    float* ws  = (float*)d_ws;

    float*  outL = out;                                  // [500 * 65536]
    float*  outJ = out + (size_t)STEPS * DIM;            // [500 * 65536]
    float*  outZ = out + 2ull * STEPS * DIM;             // [500]

    dot_partials<<<64, 256, 0, stream>>>(vL, vJ, ws);
    recurrence<<<1, 64, 0, stream>>>(ws, outZ);
    expand<<<STEPS * CHUNKS, 256, 0, stream>>>(vL, vJ, ws,
                                               (vfloat4*)outL, (vfloat4*)outJ);
}

// Round 3
// 314.120 us; speedup vs baseline: 1.0126x; 1.0126x over previous
//
#include <hip/hip_runtime.h>

// CognitiveLorenzField: 500-step scan over DIM=65536 vectors.
// Exact 2D-subspace reduction: vL_t = p_t*vL0, vJ_t = q_t*vL0 + r_t*vJ0.
// Only two dot products (L00, L01) are needed; the per-step update is scalar.
// The timed cost is streaming 262 MB of output writes (memory-bound).
//
// R2 -> R3: dropped nontemporal stores (harness fill proves plain stores
// sustain 78% HBM peak; nt suspected of throttling streaming writes), and
// reshaped expand: 4000 blocks x 2048 float4, t uniform per block, unroll 8.

#define DIM 65536
#define STEPS 500
#define DIM4 (DIM / 4)            // 16384 float4 per vector
#define BLK_F4 2048               // float4 per expand block (8 blocks per step-row)
#define TOTAL_F4 (STEPS * DIM4)   // 8,192,000

typedef float vfloat4 __attribute__((ext_vector_type(4)));

__device__ constexpr float ALPHA0 = 1.0f;
__device__ constexpr float BETA_GAME = 0.2f;
__device__ constexpr float GAMMA_C = 0.5f;
__device__ constexpr float SIGMA = 10.0f;
__device__ constexpr float RHO = 28.0f;
__device__ constexpr float LORENZ_BETA = 8.0f / 3.0f;
__device__ constexpr float DT = 0.01f;
__device__ constexpr float EPS = 1e-8f;

// ws layout (floats):
//   [0..63]      per-block partial of vL0.vL0
//   [64..127]    per-block partial of vL0.vJ0
//   [128..627]   p[t]
//   [628..1127]  q[t]
//   [1128..1627] r[t]

__global__ __launch_bounds__(256) void dot_partials(const vfloat4* __restrict__ vL,
                                                    const vfloat4* __restrict__ vJ,
                                                    float* __restrict__ ws) {
    int tid = threadIdx.x;
    int idx = blockIdx.x * 256 + tid;          // 64 blocks * 256 = 16384 = DIM4
    vfloat4 a = vL[idx];
    vfloat4 b = vJ[idx];
    float sL  = a.x * a.x + a.y * a.y + a.z * a.z + a.w * a.w;
    float sLJ = a.x * b.x + a.y * b.y + a.z * b.z + a.w * b.w;
    #pragma unroll
    for (int off = 32; off > 0; off >>= 1) {
        sL  += __shfl_down(sL,  off, 64);
        sLJ += __shfl_down(sLJ, off, 64);
    }
    __shared__ float redL[4], redLJ[4];
    int wave = tid >> 6;
    if ((tid & 63) == 0) { redL[wave] = sL; redLJ[wave] = sLJ; }
    __syncthreads();
    if (tid == 0) {
        ws[blockIdx.x]      = redL[0] + redL[1] + redL[2] + redL[3];
        ws[64 + blockIdx.x] = redLJ[0] + redLJ[1] + redLJ[2] + redLJ[3];
    }
}

__global__ __launch_bounds__(64) void recurrence(float* __restrict__ ws,
                                                 float* __restrict__ outZ) {
    int tid = threadIdx.x;                      // one wave of 64
    float sL  = ws[tid];
    float sLJ = ws[64 + tid];
    #pragma unroll
    for (int off = 32; off > 0; off >>= 1) {
        sL  += __shfl_down(sL,  off, 64);
        sLJ += __shfl_down(sLJ, off, 64);
    }
    if (tid != 0) return;
    const float L00 = sL;
    const float L01 = sLJ;
    float* pA = ws + 128;
    float* qA = ws + 628;
    float* rA = ws + 1128;
    float x = 1.f, y = 1.f, z = 1.f;
    float p = 1.f, q = 0.f, r = 1.f;
    for (int t = 0; t < STEPS; ++t) {
        float dx = SIGMA * (y - x);
        float dy = x * (RHO - z) - y;
        float dz = x * y - LORENZ_BETA * z;
        x += DT * dx;
        y += DT * dy;
        z += DT * dz;
        float alpha = ALPHA0 + GAMMA_C * z;
        float dot = p * (q * L00 + r * L01);
        float nsq = p * p * L00 + EPS;
        float c   = dot * __builtin_amdgcn_rcpf(nsq);
        float pn = p * (1.0f + DT * (alpha * (c - 1.0f) + BETA_GAME));
        float decay = 1.0f - DT * (alpha + BETA_GAME);
        float qn = q * decay + DT * p * (alpha * c + BETA_GAME);
        float rn = r * decay;
        p = pn; q = qn; r = rn;
        pA[t] = p; qA[t] = q; rA[t] = r;
        outZ[t] = z;
    }
}

// 4000 blocks; each handles BLK_F4=2048 consecutive float4 of the flat
// [500 x 16384] float4 output. 2048 divides 16384 -> t is uniform per block.
__global__ __launch_bounds__(256) void expand(const vfloat4* __restrict__ vL,
                                              const vfloat4* __restrict__ vJ,
                                              const float* __restrict__ ws,
                                              vfloat4* __restrict__ outL,
                                              vfloat4* __restrict__ outJ) {
    int b = blockIdx.x;
    int t = b >> 3;                       // 8 blocks per step-row
    float p = ws[128 + t];
    float q = ws[628 + t];
    float r = ws[1128 + t];
    int  jbase = (b & 7) * BLK_F4;        // float4 offset within the vector
    long fbase = (long)b * BLK_F4;        // flat float4 offset in output
    int  tid = threadIdx.x;
    #pragma unroll
    for (int k = 0; k < 8; ++k) {
        int j = jbase + k * 256 + tid;    // lane-contiguous, coalesced
        vfloat4 a = vL[j];
        vfloat4 v = vJ[j];
        long f = fbase + k * 256 + tid;
        outL[f]            = p * a;
        outJ[f]            = q * a + r * v;
    }
}

extern "C" void kernel_launch(void* const* d_in, const int* in_sizes, int n_in,
                              void* d_out, int out_size, void* d_ws, size_t ws_size,
                              hipStream_t stream) {
    const vfloat4* vL = (const vfloat4*)d_in[0];
    const vfloat4* vJ = (const vfloat4*)d_in[1];
    float* out = (float*)d_out;
    float* ws  = (float*)d_ws;

    float*  outL = out;                                  // [500 * 65536]
    float*  outJ = out + (size_t)STEPS * DIM;            // [500 * 65536]
    float*  outZ = out + 2ull * STEPS * DIM;             // [500]

    dot_partials<<<64, 256, 0, stream>>>(vL, vJ, ws);
    recurrence<<<1, 64, 0, stream>>>(ws, outZ);
    expand<<<TOTAL_F4 / BLK_F4, 256, 0, stream>>>(vL, vJ, ws,
                                                  (vfloat4*)outL, (vfloat4*)outJ);
}